// Round 15
// baseline (267.213 us; speedup 1.0000x reference)
//
#include <hip/hip_runtime.h>
#include <hip/hip_cooperative_groups.h>

namespace cg = cooperative_groups;

#define B_ 2
#define N_ 10000
#define E_ 150000
#define C_ 256
#define M_EDGE (B_*E_)   // 300000
#define M_NODE (B_*N_)   // 20000
#define ED_CAP (M_EDGE + 3*M_NODE + 64)   // padded CSR capacity + tail slack
#define NW_ 4096                           // k_agg streams
#define SPAN_CAP 256                       // max padded slots per stream (measured ~133)
#define EPS_ 1e-5f

typedef unsigned short u16;
typedef unsigned int   u32;
typedef unsigned long long u64;
typedef __attribute__((ext_vector_type(8))) __bf16 bf16x8;
typedef __attribute__((ext_vector_type(4))) float  f32x4;
typedef _Float16 h2 __attribute__((ext_vector_type(2)));

__device__ __forceinline__ u16 f2bf(float x) {
  union { float f; u32 u; } v; v.f = x;
  u32 r = v.u + 0x7FFFu + ((v.u >> 16) & 1u);   // RNE
  return (u16)(r >> 16);
}
__device__ __forceinline__ float bf2f(u16 x) {
  union { u32 u; float f; } v; v.u = ((u32)x) << 16; return v.f;
}
__device__ __forceinline__ u16 f2h(float x) {
  _Float16 h = (_Float16)x;
  union { _Float16 h; u16 u; } v; v.h = h; return v.u;
}
__device__ __forceinline__ float h2f(u32 bits) {
  union { u16 u; _Float16 h; } v; v.u = (u16)bits; return (float)v.h;
}
__device__ __forceinline__ h2 u2h2(u32 x) {
  union { u32 u; h2 h; } v; v.u = x; return v.h;
}
__device__ __forceinline__ u32 h22u(h2 x) {
  union { h2 h; u32 u; } v; v.h = x; return v.u;
}

__device__ __forceinline__ void async16(void* lds, const void* g) {
  __builtin_amdgcn_global_load_lds(
      (const __attribute__((address_space(1))) void*)g,
      (__attribute__((address_space(3))) void*)lds, 16, 0, 0);
}

// asm z-gather: per-lane 4B load, manually counted via vmcnt (compiler can't reorder/drain)
__device__ __forceinline__ u32 zload(const u16* zp, u32 si) {
  u32 r;
  u64 a = (u64)(zp + ((size_t)si << 8));
  asm volatile("global_load_dword %0, %1, off" : "=v"(r) : "v"(a) : "memory");
  return r;
}

// ---- fused: feat [B][C][N] f32 -> vf [B][N][C] bf16 (z<2); W transpose (z==2);
// ---- also zero counts+stats (y==0, z==0 blocks) ----
__global__ void k_transpose_feat(const float* __restrict__ f, u16* __restrict__ vf,
                                 const float* __restrict__ We, const float* __restrict__ Wu,
                                 u16* __restrict__ WeT, u16* __restrict__ WuT,
                                 int* __restrict__ counts, float* __restrict__ stats) {
  __shared__ float tile[32][33];
  int tx = threadIdx.x & 31, ty = threadIdx.x >> 5;
  if (blockIdx.z == 2) {                         // weight transpose: 128 active blocks
    if (blockIdx.y != 0 || blockIdx.x >= 128) return;
    int idx = blockIdx.x;
    const float* src = (idx >= 64) ? Wu : We;
    u16* dst = (idx >= 64) ? WuT : WeT;
    int rem = idx & 63;
    int r0 = (rem >> 3) * 32, c0 = (rem & 7) * 32;
    #pragma unroll
    for (int i = 0; i < 4; i++)
      tile[ty + i*8][tx] = src[(size_t)(r0 + ty + i*8)*C_ + c0 + tx];
    __syncthreads();
    #pragma unroll
    for (int i = 0; i < 4; i++)
      dst[(size_t)(c0 + ty + i*8)*C_ + r0 + tx] = f2bf(tile[tx][ty + i*8]);
    return;
  }
  int b = blockIdx.z, c0 = blockIdx.y * 32, n0 = blockIdx.x * 32;
  if (blockIdx.y == 0 && blockIdx.z == 0) {
    int i = blockIdx.x * 256 + threadIdx.x;
    if (i < M_NODE) counts[i] = 0;
    if (i < 1024) stats[i] = 0.f;
  }
  #pragma unroll
  for (int i = 0; i < 4; i++) {
    int c = c0 + ty + i*8, n = n0 + tx;
    tile[ty + i*8][tx] = (n < N_) ? f[((size_t)(b*C_ + c))*N_ + n] : 0.f;
  }
  __syncthreads();
  #pragma unroll
  for (int i = 0; i < 4; i++) {
    int n = n0 + ty + i*8, c = c0 + tx;
    if (n < N_) vf[((size_t)(b*N_ + n))*C_ + c] = f2bf(tile[tx][ty + i*8]);
  }
}

// ---- cooperative graph build: hist -> scan -> scatter -> pad (3 grid syncs) ----
__global__ __launch_bounds__(512)
void k_graph(const int* __restrict__ edges, const float* __restrict__ xyz,
             int* __restrict__ counts, int* __restrict__ offs, int* __restrict__ cursor,
             uint2* __restrict__ ed, u32* __restrict__ nodeInfo,
             int* __restrict__ waveStart)
{
  cg::grid_group grid = cg::this_grid();
  const int tid = threadIdx.x;
  const int gsz = gridDim.x * 512;
  const int gid = blockIdx.x * 512 + tid;

  // A: histogram of dst
  for (int i = gid; i < M_EDGE; i += gsz) {
    int b = (i >= E_) ? 1 : 0;
    int e = i - b * E_;
    int d = edges[(size_t)(b*2 + 1)*E_ + e];
    atomicAdd(&counts[b*N_ + d], 1);
  }
  grid.sync();

  // B: exclusive scan of PADDED counts (block 0, 500 threads x 40 nodes)
  if (blockIdx.x == 0) {
    __shared__ int wsum[8];
    int lane = tid & 63, wv = tid >> 6;
    int base = tid * 40;
    int local[40];
    int tot = 0;
    if (tid < 500) {
      #pragma unroll
      for (int j = 0; j < 10; j++) {
        int4 v = *(const int4*)&counts[base + j*4];
        int p0 = (v.x + 3) & ~3, p1 = (v.y + 3) & ~3;
        int p2 = (v.z + 3) & ~3, p3 = (v.w + 3) & ~3;
        local[j*4+0] = tot; tot += p0;
        local[j*4+1] = tot; tot += p1;
        local[j*4+2] = tot; tot += p2;
        local[j*4+3] = tot; tot += p3;
      }
    }
    int inc = tot;
    #pragma unroll
    for (int d = 1; d < 64; d <<= 1) {
      int v = __shfl_up(inc, d, 64);
      if (lane >= d) inc += v;
    }
    if (lane == 63) wsum[wv] = inc;
    __syncthreads();
    if (tid < 8) {
      int v = wsum[tid];
      int s = v;
      #pragma unroll
      for (int d = 1; d < 8; d <<= 1) {
        int x = __shfl_up(s, d, 64);
        if (tid >= d) s += x;
      }
      wsum[tid] = s - v;                  // exclusive wave base
    }
    __syncthreads();
    int excl = wsum[wv] + inc - tot;      // exclusive thread prefix
    if (tid < 500) {
      #pragma unroll
      for (int j = 0; j < 10; j++) {
        int4 o;
        o.x = excl + local[j*4+0];
        o.y = excl + local[j*4+1];
        o.z = excl + local[j*4+2];
        o.w = excl + local[j*4+3];
        *(int4*)&offs[base + j*4]   = o;
        *(int4*)&cursor[base + j*4] = o;
      }
    }
    if (tid == 511) offs[M_NODE] = excl;  // tot==0 for tid>=500 -> excl == grand total
  }
  grid.sync();

  // C: scatter edges into padded CSR slots (packed 8B records)
  for (int i = gid; i < M_EDGE; i += gsz) {
    int b = (i >= E_) ? 1 : 0;
    int e = i - b * E_;
    int s = edges[(size_t)(b*2 + 0)*E_ + e];
    int d = edges[(size_t)(b*2 + 1)*E_ + e];
    const float* ps = xyz + ((size_t)(b*N_ + s))*3;
    const float* pd = xyz + ((size_t)(b*N_ + d))*3;
    int pos = atomicAdd(&cursor[b*N_ + d], 1);
    u32 rx = (u32)f2h(ps[0]-pd[0]) | ((u32)f2h(ps[1]-pd[1]) << 16);
    u32 ry = (u32)f2h(ps[2]-pd[2]) | ((u32)(b*N_ + s) << 16);
    ed[pos] = make_uint2(rx, ry);
  }
  grid.sync();

  // D: pad dup fill + nodeInfo + waveStart + tail fill
  const int T = offs[M_NODE];
  const int SPW = (T + NW_ - 1) / NW_;
  for (int i = gid; i < M_NODE; i += gsz) {
    int s = offs[i], e2 = offs[i+1];
    int cnt = counts[i];
    if (cnt > 0) {
      int pad = e2 - (s + cnt);
      if (pad) {
        uint2 f = ed[s];
        for (int k = 0; k < pad; k++) ed[s + cnt + k] = f;
      }
    }
    nodeInfo[i] = ((u32)e2 << 10) | (u32)cnt;
    int lo = (i == 0) ? 0 : offs[i-1] + 1;
    int wlo = (lo + SPW - 1) / SPW;
    int whi = offs[i] / SPW;
    for (int w2 = wlo; w2 <= whi && w2 <= NW_; w2++) waveStart[w2] = i;
  }
  if (gid == 0) {
    nodeInfo[M_NODE]   = ((u32)T << 10);
    nodeInfo[M_NODE+1] = ((u32)T << 10);
    int lo = offs[M_NODE-1] + 1;
    int wlo = (lo + SPW - 1) / SPW;
    if (wlo < 0) wlo = 0;
    for (int w2 = wlo; w2 <= NW_; w2++) waveStart[w2] = M_NODE;
  }
  {
    int pos = T + gid;
    if (pos < ED_CAP) ed[pos] = make_uint2(0u, 0u);   // tail: si=0, never stats-counted
  }
}

// ---------------- z GEMM: z = vf @ We[0:256] + be (fp16 out) ----------------
__global__ __launch_bounds__(256)
void k_zgemm(const u16* __restrict__ A, const u16* __restrict__ WeT,
             const float* __restrict__ be, u16* __restrict__ zh)
{
  __shared__ __align__(16) u16 As[128*32];
  __shared__ __align__(16) u16 Bs[128*32];
  const int t  = threadIdx.x;
  const int n0 = blockIdx.x * 128;
  const int mb = blockIdx.y * 128;

  int r0 = mb + (t >> 2);      if (r0 >= M_NODE) r0 = 0;
  int r1 = mb + 64 + (t >> 2); if (r1 >= M_NODE) r1 = 0;
  const int ak = (((t & 3) ^ ((t >> 3) & 3)) << 3);
  const u16* asrc0 = A + (size_t)r0 * C_ + ak;
  const u16* asrc1 = A + (size_t)r1 * C_ + ak;
  const u16* bsrc0 = WeT + (size_t)(n0 + (t >> 2)) * C_ + ak;
  const u16* bsrc1 = WeT + (size_t)(n0 + 64 + (t >> 2)) * C_ + ak;

  const f32x4 zero = {0.f, 0.f, 0.f, 0.f};
  f32x4 acc[4][4];
  #pragma unroll
  for (int m = 0; m < 4; m++)
    #pragma unroll
    for (int n = 0; n < 4; n++) acc[m][n] = zero;

  const int lane = t & 63, wave = t >> 6;
  const int wr = wave >> 1, wc = wave & 1;
  const int lr = lane & 15, lch = lane >> 4;
  const int swz = (lr >> 1) & 3;

  for (int kk = 0; kk < 8; kk++) {
    const int k0 = kk * 32;
    async16(&As[t*8],        asrc0 + k0);
    async16(&As[(t+256)*8],  asrc1 + k0);
    async16(&Bs[t*8],        bsrc0 + k0);
    async16(&Bs[(t+256)*8],  bsrc1 + k0);
    __syncthreads();
    bf16x8 a[4], b[4];
    #pragma unroll
    for (int m = 0; m < 4; m++)
      a[m] = *(const bf16x8*)&As[(wr*64 + m*16 + lr)*32 + ((lch ^ swz) << 3)];
    #pragma unroll
    for (int n = 0; n < 4; n++)
      b[n] = *(const bf16x8*)&Bs[(wc*64 + n*16 + lr)*32 + ((lch ^ swz) << 3)];
    #pragma unroll
    for (int m = 0; m < 4; m++)
      #pragma unroll
      for (int n = 0; n < 4; n++)
        acc[m][n] = __builtin_amdgcn_mfma_f32_16x16x32_bf16(a[m], b[n], acc[m][n], 0, 0, 0);
    __syncthreads();
  }

  int gc[4]; float bias[4];
  #pragma unroll
  for (int n = 0; n < 4; n++) { int c = n0 + wc*64 + n*16 + lr; gc[n] = c; bias[n] = be[c]; }
  #pragma unroll
  for (int m = 0; m < 4; m++) {
    #pragma unroll
    for (int j = 0; j < 4; j++) {
      int r = mb + wr*64 + m*16 + lch*4 + j;
      if (r < M_NODE) {
        #pragma unroll
        for (int n = 0; n < 4; n++)
          zh[(size_t)r * C_ + gc[n]] = f2h(acc[m][n][j] + bias[n]);
      }
    }
  }
}

// -------- aggregation: XCD-grouped (2x128ch), LDS records, ring-8 asm z pipeline --------
__global__ __launch_bounds__(512)
void k_agg(const u16* __restrict__ zh, const uint2* __restrict__ ed,
           const int* __restrict__ offs, const u32* __restrict__ nodeInfo,
           const int* __restrict__ waveStart,
           const float* __restrict__ We, const float* __restrict__ ge,
           u32* __restrict__ aggh, float* __restrict__ esum, float* __restrict__ esumsq)
{
  __shared__ __align__(16) uint2 rec[8][SPAN_CAP];
  __shared__ float red[8][128];

  const int tid  = threadIdx.x;
  const int lane = tid & 63;
  const int wave = __builtin_amdgcn_readfirstlane(tid >> 6);     // 0..7
  const int grp  = __builtin_amdgcn_readfirstlane(blockIdx.x & 1);
  const int c0   = grp * 128 + lane * 2;                         // 2 channels per lane
  const h2 w0 = h2{(_Float16)We[256*C_ + c0], (_Float16)We[256*C_ + c0 + 1]};
  const h2 w1 = h2{(_Float16)We[257*C_ + c0], (_Float16)We[257*C_ + c0 + 1]};
  const h2 w2 = h2{(_Float16)We[258*C_ + c0], (_Float16)We[258*C_ + c0 + 1]};
  const float ge0 = ge[c0], ge1 = ge[c0 + 1];
  const u16* zp = zh + c0;

  const h2 hzero = h2{(_Float16)0.f, (_Float16)0.f};
  const h2 MXI = h2{(_Float16)-1.f, (_Float16)-1.f};
  const h2 MNI = h2{(_Float16)65504.f, (_Float16)65504.f};
  h2 psh = hzero, pqh = hzero;                                   // packed f16 stats

  const int wid  = (blockIdx.x >> 1) * 8 + wave;                 // stream id, 4096 total
  int cur        = __builtin_amdgcn_readfirstlane(waveStart[wid]);
  const int nEnd = __builtin_amdgcn_readfirstlane(waveStart[wid + 1]);

  if (cur < nEnd) {
    const int uBeg = __builtin_amdgcn_readfirstlane(offs[cur]);
    const int uEnd = __builtin_amdgcn_readfirstlane(offs[nEnd]);
    const int span = uEnd - uBeg;
    if (span > 0) {
      // stage this wave's record range to LDS (coalesced, removes records from vmcnt queue)
      for (int s = lane; s < span; s += 64) rec[wave][s] = ed[uBeg + s];

      u32 info = nodeInfo[cur];
      while ((int)(info >> 10) == uBeg) { cur++; info = nodeInfo[cur]; }
      int curEnd   = (int)(info >> 10);
      int vE       = uBeg + (int)(info & 1023u);
      u32 nextInfo = nodeInfo[cur + 1];

      h2 mx = MXI, mn = MNI;
      const int nc = span >> 2;
      u32 Z[8][4];

      auto flushNode = [&]() {
        h2 s;
        s.x = (ge0 >= 0.f) ? mx.x : mn.x;
        s.y = (ge1 >= 0.f) ? mx.y : mn.y;
        aggh[(size_t)cur * 128 + grp * 64 + lane] = h22u(s);
      };

#define ISSUEZ(ZB, CI) { \
      int _c = (CI) < nc - 1 ? (CI) : nc - 1; \
      uint4 _a = *(const uint4*)&rec[wave][_c*4]; \
      uint4 _b = *(const uint4*)&rec[wave][_c*4 + 2]; \
      Z[ZB][0] = zload(zp, _a.y >> 16); \
      Z[ZB][1] = zload(zp, _a.w >> 16); \
      Z[ZB][2] = zload(zp, _b.y >> 16); \
      Z[ZB][3] = zload(zp, _b.w >> 16); }

#define PROCSLOT(RX, RY, ZV, KOFF) { \
      h2 dxx = u2h2(((RX) & 0xffffu) | ((RX) << 16)); \
      h2 dyy = u2h2(((RX) >> 16) | ((RX) & 0xffff0000u)); \
      h2 dzz = u2h2(((RY) & 0xffffu) | ((RY) << 16)); \
      h2 y = dxx*w0 + dyy*w1 + dzz*w2 + u2h2(ZV); \
      y = __builtin_elementwise_max(y, hzero); \
      mx = __builtin_elementwise_max(mx, y); \
      mn = __builtin_elementwise_min(mn, y); \
      if (slot + (KOFF) < vE) { psh = psh + y; pqh = y*y + pqh; } }

#define PHASE(J, ZW, ZR) { \
      uint4 rA = *(const uint4*)&rec[wave][(J)*4]; \
      uint4 rB = *(const uint4*)&rec[wave][(J)*4 + 2]; \
      ISSUEZ(ZW, (J) + 5) \
      asm volatile("s_waitcnt vmcnt(20)" ::: "memory"); \
      __builtin_amdgcn_sched_barrier(0); \
      const int slot = uBeg + (J)*4; \
      if (slot == curEnd) { \
        flushNode(); \
        mx = MXI; mn = MNI; \
        cur++; \
        u32 inf = nextInfo; \
        while ((int)(inf >> 10) == curEnd) { cur++; inf = nodeInfo[cur]; } \
        vE = curEnd + (int)(inf & 1023u); \
        curEnd = (int)(inf >> 10); \
        nextInfo = nodeInfo[cur + 1]; \
      } \
      PROCSLOT(rA.x, rA.y, Z[ZR][0], 0) \
      PROCSLOT(rA.z, rA.w, Z[ZR][1], 1) \
      PROCSLOT(rB.x, rB.y, Z[ZR][2], 2) \
      PROCSLOT(rB.z, rB.w, Z[ZR][3], 3) }

      // prologue: z for chunks 0..4 (20 loads in flight, 5-phase lead)
      ISSUEZ(0, 0) ISSUEZ(1, 1) ISSUEZ(2, 2) ISSUEZ(3, 3) ISSUEZ(4, 4)

      for (int j = 0; j < nc; j += 8) {
        PHASE(j + 0, 5, 0)
        if (j + 1 < nc) PHASE(j + 1, 6, 1)
        if (j + 2 < nc) PHASE(j + 2, 7, 2)
        if (j + 3 < nc) PHASE(j + 3, 0, 3)
        if (j + 4 < nc) PHASE(j + 4, 1, 4)
        if (j + 5 < nc) PHASE(j + 5, 2, 5)
        if (j + 6 < nc) PHASE(j + 6, 3, 6)
        if (j + 7 < nc) PHASE(j + 7, 4, 7)
      }
      flushNode();
#undef ISSUEZ
#undef PROCSLOT
#undef PHASE
    }
  }

  // block-level stats reduction: block covers channels [grp*128, grp*128+128)
  float ps0 = (float)psh.x, ps1 = (float)psh.y;
  float pq0 = (float)pqh.x, pq1 = (float)pqh.y;
  red[wave][lane*2]     = ps0;
  red[wave][lane*2 + 1] = ps1;
  __syncthreads();
  if (tid < 128) {
    float s = 0.f;
    #pragma unroll
    for (int w = 0; w < 8; w++) s += red[w][tid];
    atomicAdd(&esum[grp*128 + tid], s);
  }
  __syncthreads();
  red[wave][lane*2]     = pq0;
  red[wave][lane*2 + 1] = pq1;
  __syncthreads();
  if (tid < 128) {
    float s = 0.f;
    #pragma unroll
    for (int w = 0; w < 8; w++) s += red[w][tid];
    atomicAdd(&esumsq[grp*128 + tid], s);
  }
}

// --- u GEMM (fused BN-e stats + aggnorm): A = BN(aggh) on-the-fly; y=relu(A@Wu+b) ---
__global__ __launch_bounds__(256)
void k_ugemm(const u32* __restrict__ aggh, const int* __restrict__ counts,
             const float* __restrict__ esum, const float* __restrict__ esumsq,
             const float* __restrict__ ge, const float* __restrict__ bte,
             const u16* __restrict__ WuT, const float* __restrict__ bu,
             u16* __restrict__ yu, float* __restrict__ usum, float* __restrict__ usumsq)
{
  __shared__ __align__(16) u16 As[128*32];
  __shared__ __align__(16) u16 Bs[128*32];
  __shared__ float sscale[256], sshift[256];
  const int t  = threadIdx.x;
  const int n0 = blockIdx.x * 128;
  const int mb = blockIdx.y * 128;

  {  // fused k_stats_e (redundant per block, trivial)
    float m = esum[t] / (float)M_EDGE;
    float v = esumsq[t] / (float)M_EDGE - m*m;
    v = fmaxf(v, 0.f);
    float s = ge[t] * rsqrtf(v + EPS_);
    sscale[t] = s;
    sshift[t] = bte[t] - m*s;
  }

  int r0 = mb + (t >> 2);      if (r0 >= M_NODE) r0 = 0;
  int r1 = mb + 64 + (t >> 2); if (r1 >= M_NODE) r1 = 0;
  const int ak = (((t & 3) ^ ((t >> 3) & 3)) << 3);
  const bool nz0 = counts[r0] > 0;
  const bool nz1 = counts[r1] > 0;
  const u32* ag0 = aggh + (size_t)r0 * 128 + (ak >> 1);
  const u32* ag1 = aggh + (size_t)r1 * 128 + (ak >> 1);
  const u16* bsrc0 = WuT + (size_t)(n0 + (t >> 2)) * C_ + ak;
  const u16* bsrc1 = WuT + (size_t)(n0 + 64 + (t >> 2)) * C_ + ak;

  const f32x4 zero = {0.f, 0.f, 0.f, 0.f};
  f32x4 acc[4][4];
  #pragma unroll
  for (int m = 0; m < 4; m++)
    #pragma unroll
    for (int n = 0; n < 4; n++) acc[m][n] = zero;

  const int lane = t & 63, wave = t >> 6;
  const int wr = wave >> 1, wc = wave & 1;
  const int lr = lane & 15, lch = lane >> 4;
  const int swz = (lr >> 1) & 3;

  __syncthreads();   // sscale/sshift ready

  for (int kk = 0; kk < 8; kk++) {
    const int k0 = kk * 32;
    // A staging: packed-f16 aggh -> BN affine -> bf16 tile (replaces k_aggnorm)
    uint4 a0 = *(const uint4*)(ag0 + (k0 >> 1));
    uint4 a1 = *(const uint4*)(ag1 + (k0 >> 1));
    const int base = k0 + ak;
    float4 sc0 = *(const float4*)&sscale[base];
    float4 sc1 = *(const float4*)&sscale[base + 4];
    float4 sh0 = *(const float4*)&sshift[base];
    float4 sh1 = *(const float4*)&sshift[base + 4];
    auto cvt = [&](u32 q, float s0, float b0, float s1, float b1, bool nz) -> u32 {
      float v0 = nz ? fmaf(h2f(q & 0xffffu), s0, b0) : 0.f;
      float v1 = nz ? fmaf(h2f(q >> 16),     s1, b1) : 0.f;
      return ((u32)f2bf(v0)) | (((u32)f2bf(v1)) << 16);
    };
    uint4 p0, p1;
    p0.x = cvt(a0.x, sc0.x, sh0.x, sc0.y, sh0.y, nz0);
    p0.y = cvt(a0.y, sc0.z, sh0.z, sc0.w, sh0.w, nz0);
    p0.z = cvt(a0.z, sc1.x, sh1.x, sc1.y, sh1.y, nz0);
    p0.w = cvt(a0.w, sc1.z, sh1.z, sc1.w, sh1.w, nz0);
    p1.x = cvt(a1.x, sc0.x, sh0.x, sc0.y, sh0.y, nz1);
    p1.y = cvt(a1.y, sc0.z, sh0.z, sc0.w, sh0.w, nz1);
    p1.z = cvt(a1.z, sc1.x, sh1.x, sc1.y, sh1.y, nz1);
    p1.w = cvt(a1.w, sc1.z, sh1.z, sc1.w, sh1.w, nz1);
    *(uint4*)&As[t*8]       = p0;
    *(uint4*)&As[(t+256)*8] = p1;
    async16(&Bs[t*8],        bsrc0 + k0);
    async16(&Bs[(t+256)*8],  bsrc1 + k0);
    __syncthreads();
    bf16x8 a[4], b[4];
    #pragma unroll
    for (int m = 0; m < 4; m++)
      a[m] = *(const bf16x8*)&As[(wr*64 + m*16 + lr)*32 + ((lch ^ swz) << 3)];
    #pragma unroll
    for (int n = 0; n < 4; n++)
      b[n] = *(const bf16x8*)&Bs[(wc*64 + n*16 + lr)*32 + ((lch ^ swz) << 3)];
    #pragma unroll
    for (int m = 0; m < 4; m++)
      #pragma unroll
      for (int n = 0; n < 4; n++)
        acc[m][n] = __builtin_amdgcn_mfma_f32_16x16x32_bf16(a[m], b[n], acc[m][n], 0, 0, 0);
    __syncthreads();
  }

  int gc[4]; float bias[4];
  #pragma unroll
  for (int n = 0; n < 4; n++) { int c = n0 + wc*64 + n*16 + lr; gc[n] = c; bias[n] = bu[c]; }
  float psum[4] = {0.f,0.f,0.f,0.f};
  float psq [4] = {0.f,0.f,0.f,0.f};
  #pragma unroll
  for (int m = 0; m < 4; m++) {
    #pragma unroll
    for (int j = 0; j < 4; j++) {
      int r = mb + wr*64 + m*16 + lch*4 + j;
      bool valid = r < M_NODE;
      #pragma unroll
      for (int n = 0; n < 4; n++) {
        float y = fmaxf(acc[m][n][j] + bias[n], 0.f);
        if (valid) {
          psum[n] += y;
          psq[n]  += y*y;
          yu[(size_t)r * C_ + gc[n]] = f2bf(y);
        }
      }
    }
  }
  #pragma unroll
  for (int n = 0; n < 4; n++) {
    float s1 = psum[n], s2 = psq[n];
    s1 += __shfl_xor(s1, 16, 64);  s2 += __shfl_xor(s2, 16, 64);
    s1 += __shfl_xor(s1, 32, 64);  s2 += __shfl_xor(s2, 32, 64);
    if (lch == 0) { atomicAdd(&usum[gc[n]], s1); atomicAdd(&usumsq[gc[n]], s2); }
  }
}

// -- final (fused BN-u stats): BN affine + residual (bf16 vf) + transpose to [B][C][N] --
__global__ void k_final(const u16* __restrict__ yu, const u16* __restrict__ vf,
                        const float* __restrict__ usum, const float* __restrict__ usumsq,
                        const float* __restrict__ gu, const float* __restrict__ btu,
                        float* __restrict__ out) {
  __shared__ float tile[32][33];
  __shared__ float sc[32], sh[32];
  int tx = threadIdx.x & 31, ty = threadIdx.x >> 5;
  int b = blockIdx.z, c0 = blockIdx.y * 32, n0 = blockIdx.x * 32;
  if (threadIdx.x < 32) {   // fused k_stats_u for this block's 32 channels
    int c = c0 + threadIdx.x;
    float m = usum[c] / (float)M_NODE;
    float v = usumsq[c] / (float)M_NODE - m*m;
    v = fmaxf(v, 0.f);
    float s = gu[c] * rsqrtf(v + EPS_);
    sc[threadIdx.x] = s;
    sh[threadIdx.x] = btu[c] - m*s;
  }
  __syncthreads();
  #pragma unroll
  for (int i = 0; i < 4; i++) {
    int n = n0 + ty + i*8, c = c0 + tx;
    float v = 0.f;
    if (n < N_) {
      size_t idx = ((size_t)(b*N_ + n))*C_ + c;
      v = bf2f(yu[idx]) * sc[tx] + sh[tx] + bf2f(vf[idx]);
    }
    tile[ty + i*8][tx] = v;
  }
  __syncthreads();
  int n = n0 + tx;
  if (n < N_) {
    #pragma unroll
    for (int i = 0; i < 4; i++) {
      int c = c0 + ty + i*8;
      out[((size_t)(b*C_ + c))*N_ + n] = tile[tx][ty + i*8];
    }
  }
}

extern "C" void kernel_launch(void* const* d_in, const int* in_sizes, int n_in,
                              void* d_out, int out_size, void* d_ws, size_t ws_size,
                              hipStream_t stream) {
  const float* xyz  = (const float*)d_in[0];
  const float* feat = (const float*)d_in[1];
  const int*   edges= (const int*)  d_in[2];
  const float* We   = (const float*)d_in[3];
  const float* be   = (const float*)d_in[4];
  const float* ge   = (const float*)d_in[5];
  const float* bte  = (const float*)d_in[6];
  const float* Wu   = (const float*)d_in[7];
  const float* bu   = (const float*)d_in[8];
  const float* gu   = (const float*)d_in[9];
  const float* btu  = (const float*)d_in[10];
  float* out = (float*)d_out;

  char* w = (char*)d_ws;
  size_t off = 0;
  auto carve = [&](size_t bytes) -> void* {
    void* p = w + off;
    off = (off + bytes + 511) & ~(size_t)511;
    return p;
  };
  u16*  vf       = (u16*) carve((size_t)M_NODE*C_*2);       // 10.24 MB
  u16*  WeT      = (u16*) carve((size_t)C_*C_*2);
  u16*  WuT      = (u16*) carve((size_t)C_*C_*2);
  u16*  zh       = (u16*) carve((size_t)M_NODE*C_*2);       // 10.24 MB (fp16)
  uint2* ed      = (uint2*)carve((size_t)ED_CAP*8);         // 2.9 MB
  int*  counts   = (int*) carve((size_t)M_NODE*4);
  int*  offs     = (int*) carve((size_t)(M_NODE+1)*4);
  int*  cursor   = (int*) carve((size_t)M_NODE*4);
  u32*  nodeInfo = (u32*) carve((size_t)(M_NODE+2)*4);
  int*  waveStart= (int*) carve((size_t)(NW_+1)*4);
  u32*  aggh     = (u32*) carve((size_t)M_NODE*128*4);      // 10.24 MB (packed f16)
  u16*  yu       = (u16*) carve((size_t)M_NODE*C_*2);       // 10.24 MB (bf16)
  float* stats   = (float*)carve(2048*4);
  float* esum = stats,        *esumsq = stats + 256;
  float* usum = stats + 512,  *usumsq = stats + 768;

  k_transpose_feat<<<dim3((N_+31)/32, C_/32, 3), 256, 0, stream>>>(
      feat, vf, We, Wu, WeT, WuT, counts, stats);
  {
    void* args[] = { (void*)&edges, (void*)&xyz, (void*)&counts, (void*)&offs,
                     (void*)&cursor, (void*)&ed, (void*)&nodeInfo, (void*)&waveStart };
    hipLaunchCooperativeKernel((const void*)k_graph, dim3(320), dim3(512),
                               args, 0, stream);
  }
  k_zgemm<<<dim3(2, (M_NODE + 127)/128), 256, 0, stream>>>(vf, WeT, be, zh);
  k_agg<<<dim3(NW_/8*2), 512, 0, stream>>>(zh, ed, offs, nodeInfo, waveStart,
                                           We, ge, aggh, esum, esumsq);
  k_ugemm<<<dim3(2, (M_NODE + 127)/128), 256, 0, stream>>>(
      aggh, counts, esum, esumsq, ge, bte, WuT, bu, yu, usum, usumsq);
  k_final<<<dim3((N_+31)/32, C_/32, B_), 256, 0, stream>>>(
      yu, vf, usum, usumsq, gu, btu, out);
}

// Round 16
// 140.322 us; speedup vs baseline: 1.9043x; 1.9043x over previous
//
#include <hip/hip_runtime.h>

#define B_ 2
#define N_ 10000
#define E_ 150000
#define C_ 256
#define M_EDGE (B_*E_)   // 300000
#define M_NODE (B_*N_)   // 20000
#define ED_CAP (M_EDGE + 3*M_NODE + 64)   // padded CSR capacity + tail slack
#define NW_ 4096                           // k_agg streams
#define SPAN_CAP 256                       // max padded slots per stream (measured ~133)
#define EPS_ 1e-5f

typedef unsigned short u16;
typedef unsigned int   u32;
typedef unsigned long long u64;
typedef __attribute__((ext_vector_type(8))) __bf16 bf16x8;
typedef __attribute__((ext_vector_type(4))) float  f32x4;
typedef _Float16 h2 __attribute__((ext_vector_type(2)));

__device__ __forceinline__ u16 f2bf(float x) {
  union { float f; u32 u; } v; v.f = x;
  u32 r = v.u + 0x7FFFu + ((v.u >> 16) & 1u);   // RNE
  return (u16)(r >> 16);
}
__device__ __forceinline__ float bf2f(u16 x) {
  union { u32 u; float f; } v; v.u = ((u32)x) << 16; return v.f;
}
__device__ __forceinline__ u16 f2h(float x) {
  _Float16 h = (_Float16)x;
  union { _Float16 h; u16 u; } v; v.h = h; return v.u;
}
__device__ __forceinline__ float h2f(u32 bits) {
  union { u16 u; _Float16 h; } v; v.u = (u16)bits; return (float)v.h;
}
__device__ __forceinline__ h2 u2h2(u32 x) {
  union { u32 u; h2 h; } v; v.u = x; return v.h;
}
__device__ __forceinline__ u32 h22u(h2 x) {
  union { h2 h; u32 u; } v; v.h = x; return v.u;
}

__device__ __forceinline__ void async16(void* lds, const void* g) {
  __builtin_amdgcn_global_load_lds(
      (const __attribute__((address_space(1))) void*)g,
      (__attribute__((address_space(3))) void*)lds, 16, 0, 0);
}

// asm z-gather: per-lane 4B load, manually counted via vmcnt (compiler can't reorder/drain)
__device__ __forceinline__ u32 zload(const u16* zp, u32 si) {
  u32 r;
  u64 a = (u64)(zp + ((size_t)si << 8));
  asm volatile("global_load_dword %0, %1, off" : "=v"(r) : "v"(a) : "memory");
  return r;
}

// ---- fused: feat [B][C][N] f32 -> vf [B][N][C] bf16 (z<2); W transpose (z==2);
// ---- also zero counts+stats (y==0, z==0 blocks) ----
__global__ void k_transpose_feat(const float* __restrict__ f, u16* __restrict__ vf,
                                 const float* __restrict__ We, const float* __restrict__ Wu,
                                 u16* __restrict__ WeT, u16* __restrict__ WuT,
                                 int* __restrict__ counts, float* __restrict__ stats) {
  __shared__ float tile[32][33];
  int tx = threadIdx.x & 31, ty = threadIdx.x >> 5;
  if (blockIdx.z == 2) {                         // weight transpose: 128 active blocks
    if (blockIdx.y != 0 || blockIdx.x >= 128) return;
    int idx = blockIdx.x;
    const float* src = (idx >= 64) ? Wu : We;
    u16* dst = (idx >= 64) ? WuT : WeT;
    int rem = idx & 63;
    int r0 = (rem >> 3) * 32, c0 = (rem & 7) * 32;
    #pragma unroll
    for (int i = 0; i < 4; i++)
      tile[ty + i*8][tx] = src[(size_t)(r0 + ty + i*8)*C_ + c0 + tx];
    __syncthreads();
    #pragma unroll
    for (int i = 0; i < 4; i++)
      dst[(size_t)(c0 + ty + i*8)*C_ + r0 + tx] = f2bf(tile[tx][ty + i*8]);
    return;
  }
  int b = blockIdx.z, c0 = blockIdx.y * 32, n0 = blockIdx.x * 32;
  if (blockIdx.y == 0 && blockIdx.z == 0) {
    int i = blockIdx.x * 256 + threadIdx.x;
    if (i < M_NODE) counts[i] = 0;
    if (i < 1024) stats[i] = 0.f;
  }
  #pragma unroll
  for (int i = 0; i < 4; i++) {
    int c = c0 + ty + i*8, n = n0 + tx;
    tile[ty + i*8][tx] = (n < N_) ? f[((size_t)(b*C_ + c))*N_ + n] : 0.f;
  }
  __syncthreads();
  #pragma unroll
  for (int i = 0; i < 4; i++) {
    int n = n0 + ty + i*8, c = c0 + tx;
    if (n < N_) vf[((size_t)(b*N_ + n))*C_ + c] = f2bf(tile[tx][ty + i*8]);
  }
}

// ---------------- histogram of dst ----------------
__global__ void k_hist(const int* __restrict__ edges, int* __restrict__ counts) {
  int i = blockIdx.x * 256 + threadIdx.x;
  if (i >= M_EDGE) return;
  int b = (i >= E_) ? 1 : 0;
  int e = i - b * E_;
  int d = edges[(size_t)(b*2 + 1)*E_ + e];
  atomicAdd(&counts[b*N_ + d], 1);
}

// ------- exclusive scan of PADDED counts (single block, wave-shuffle: 2 barriers) -------
__global__ __launch_bounds__(1024)
void k_scan(const int* __restrict__ counts, int* __restrict__ offs, int* __restrict__ cursor) {
  __shared__ int wsum[16];
  int t = threadIdx.x;
  int lane = t & 63, wv = t >> 6;
  int base = t * 20;
  int vals[20];
  if (t < 1000) {
    #pragma unroll
    for (int j = 0; j < 5; j++)
      *(int4*)&vals[j*4] = *(const int4*)&counts[base + j*4];
  } else {
    #pragma unroll
    for (int i = 0; i < 20; i++) vals[i] = 0;
  }
  int local[20];
  int tot = 0;
  #pragma unroll
  for (int i = 0; i < 20; i++) {
    int pv = (vals[i] + 3) & ~3;          // pad each node to multiple of 4
    local[i] = tot; tot += pv;
  }
  // wave-inclusive scan of thread totals (no barriers)
  int inc = tot;
  #pragma unroll
  for (int d = 1; d < 64; d <<= 1) {
    int v = __shfl_up(inc, d, 64);
    if (lane >= d) inc += v;
  }
  if (lane == 63) wsum[wv] = inc;
  __syncthreads();
  if (t < 16) {
    int v = wsum[t];
    int inc2 = v;
    #pragma unroll
    for (int d = 1; d < 16; d <<= 1) {
      int x = __shfl_up(inc2, d, 16);
      if (t >= d) inc2 += x;
    }
    wsum[t] = inc2 - v;                   // exclusive wave base
  }
  __syncthreads();
  int excl = wsum[wv] + inc - tot;        // exclusive thread prefix
  if (t < 1000) {
    #pragma unroll
    for (int j = 0; j < 5; j++) {
      int4 o;
      o.x = excl + local[j*4 + 0];
      o.y = excl + local[j*4 + 1];
      o.z = excl + local[j*4 + 2];
      o.w = excl + local[j*4 + 3];
      *(int4*)&offs[base + j*4]   = o;
      *(int4*)&cursor[base + j*4] = o;
    }
  }
  if (t == 1023) offs[M_NODE] = excl + tot;   // total padded size
}

// ---------------- scatter edges into padded CSR slots (packed 8B records) ----------------
// rec.x = f16(dx) | f16(dy)<<16 ; rec.y = f16(dz) | src_node<<16
__global__ void k_scatter(const int* __restrict__ edges, const float* __restrict__ xyz,
                          int* __restrict__ cursor, uint2* __restrict__ ed) {
  int i = blockIdx.x * 256 + threadIdx.x;
  if (i >= M_EDGE) return;
  int b = (i >= E_) ? 1 : 0;
  int e = i - b * E_;
  int s = edges[(size_t)(b*2 + 0)*E_ + e];
  int d = edges[(size_t)(b*2 + 1)*E_ + e];
  const float* ps = xyz + ((size_t)(b*N_ + s))*3;
  const float* pd = xyz + ((size_t)(b*N_ + d))*3;
  int pos = atomicAdd(&cursor[b*N_ + d], 1);
  u32 rx = (u32)f2h(ps[0]-pd[0]) | ((u32)f2h(ps[1]-pd[1]) << 16);
  u32 ry = (u32)f2h(ps[2]-pd[2]) | ((u32)(b*N_ + s) << 16);
  ed[pos] = make_uint2(rx, ry);
}

// ------- pad dup fill + tail fill + nodeInfo + waveStart table -------
// nodeInfo[n] = (paddedEnd << 10) | cnt
// waveStart[w] = first node whose padded segment starts >= w*SPW
__global__ void k_pad(const int* __restrict__ offs, const int* __restrict__ counts,
                      uint2* __restrict__ ed, u32* __restrict__ nodeInfo,
                      int* __restrict__ waveStart) {
  int i = blockIdx.x * 256 + threadIdx.x;
  const int T = offs[M_NODE];
  const int SPW = (T + NW_ - 1) / NW_;
  if (i < M_NODE) {
    int s = offs[i], e = offs[i+1];
    int cnt = counts[i];
    if (cnt > 0) {
      int pad = e - (s + cnt);
      if (pad) {
        uint2 f = ed[s];
        for (int k = 0; k < pad; k++) ed[s + cnt + k] = f;
      }
    }
    nodeInfo[i] = ((u32)e << 10) | (u32)cnt;
    int lo = (i == 0) ? 0 : offs[i-1] + 1;
    int wlo = (lo + SPW - 1) / SPW;
    int whi = offs[i] / SPW;
    for (int w = wlo; w <= whi && w <= NW_; w++) waveStart[w] = i;
  }
  if (i == M_NODE) {
    nodeInfo[M_NODE]   = ((u32)T << 10);
    nodeInfo[M_NODE+1] = ((u32)T << 10);
    int lo = offs[M_NODE-1] + 1;
    int wlo = (lo + SPW - 1) / SPW;
    if (wlo < 0) wlo = 0;
    for (int w = wlo; w <= NW_; w++) waveStart[w] = M_NODE;
  }
  int pos = T + i;
  if (pos < ED_CAP) ed[pos] = make_uint2(0u, 0u);   // tail: si=0, never stats-counted
}

// ---------------- z GEMM: z = vf @ We[0:256] + be (fp16 out) ----------------
__global__ __launch_bounds__(256)
void k_zgemm(const u16* __restrict__ A, const u16* __restrict__ WeT,
             const float* __restrict__ be, u16* __restrict__ zh)
{
  __shared__ __align__(16) u16 As[128*32];
  __shared__ __align__(16) u16 Bs[128*32];
  const int t  = threadIdx.x;
  const int n0 = blockIdx.x * 128;
  const int mb = blockIdx.y * 128;

  int r0 = mb + (t >> 2);      if (r0 >= M_NODE) r0 = 0;
  int r1 = mb + 64 + (t >> 2); if (r1 >= M_NODE) r1 = 0;
  const int ak = (((t & 3) ^ ((t >> 3) & 3)) << 3);
  const u16* asrc0 = A + (size_t)r0 * C_ + ak;
  const u16* asrc1 = A + (size_t)r1 * C_ + ak;
  const u16* bsrc0 = WeT + (size_t)(n0 + (t >> 2)) * C_ + ak;
  const u16* bsrc1 = WeT + (size_t)(n0 + 64 + (t >> 2)) * C_ + ak;

  const f32x4 zero = {0.f, 0.f, 0.f, 0.f};
  f32x4 acc[4][4];
  #pragma unroll
  for (int m = 0; m < 4; m++)
    #pragma unroll
    for (int n = 0; n < 4; n++) acc[m][n] = zero;

  const int lane = t & 63, wave = t >> 6;
  const int wr = wave >> 1, wc = wave & 1;
  const int lr = lane & 15, lch = lane >> 4;
  const int swz = (lr >> 1) & 3;

  for (int kk = 0; kk < 8; kk++) {
    const int k0 = kk * 32;
    async16(&As[t*8],        asrc0 + k0);
    async16(&As[(t+256)*8],  asrc1 + k0);
    async16(&Bs[t*8],        bsrc0 + k0);
    async16(&Bs[(t+256)*8],  bsrc1 + k0);
    __syncthreads();
    bf16x8 a[4], b[4];
    #pragma unroll
    for (int m = 0; m < 4; m++)
      a[m] = *(const bf16x8*)&As[(wr*64 + m*16 + lr)*32 + ((lch ^ swz) << 3)];
    #pragma unroll
    for (int n = 0; n < 4; n++)
      b[n] = *(const bf16x8*)&Bs[(wc*64 + n*16 + lr)*32 + ((lch ^ swz) << 3)];
    #pragma unroll
    for (int m = 0; m < 4; m++)
      #pragma unroll
      for (int n = 0; n < 4; n++)
        acc[m][n] = __builtin_amdgcn_mfma_f32_16x16x32_bf16(a[m], b[n], acc[m][n], 0, 0, 0);
    __syncthreads();
  }

  int gc[4]; float bias[4];
  #pragma unroll
  for (int n = 0; n < 4; n++) { int c = n0 + wc*64 + n*16 + lr; gc[n] = c; bias[n] = be[c]; }
  #pragma unroll
  for (int m = 0; m < 4; m++) {
    #pragma unroll
    for (int j = 0; j < 4; j++) {
      int r = mb + wr*64 + m*16 + lch*4 + j;
      if (r < M_NODE) {
        #pragma unroll
        for (int n = 0; n < 4; n++)
          zh[(size_t)r * C_ + gc[n]] = f2h(acc[m][n][j] + bias[n]);
      }
    }
  }
}

// -------- aggregation: XCD-grouped (2x128ch), LDS records, ring-8 asm z pipeline --------
__global__ __launch_bounds__(512)
void k_agg(const u16* __restrict__ zh, const uint2* __restrict__ ed,
           const int* __restrict__ offs, const u32* __restrict__ nodeInfo,
           const int* __restrict__ waveStart,
           const float* __restrict__ We, const float* __restrict__ ge,
           u32* __restrict__ aggh, float* __restrict__ esum, float* __restrict__ esumsq)
{
  __shared__ __align__(16) uint2 rec[8][SPAN_CAP];
  __shared__ float red[8][128];

  const int tid  = threadIdx.x;
  const int lane = tid & 63;
  const int wave = __builtin_amdgcn_readfirstlane(tid >> 6);     // 0..7
  const int grp  = __builtin_amdgcn_readfirstlane(blockIdx.x & 1);
  const int c0   = grp * 128 + lane * 2;                         // 2 channels per lane
  const h2 w0 = h2{(_Float16)We[256*C_ + c0], (_Float16)We[256*C_ + c0 + 1]};
  const h2 w1 = h2{(_Float16)We[257*C_ + c0], (_Float16)We[257*C_ + c0 + 1]};
  const h2 w2 = h2{(_Float16)We[258*C_ + c0], (_Float16)We[258*C_ + c0 + 1]};
  const float ge0 = ge[c0], ge1 = ge[c0 + 1];
  const u16* zp = zh + c0;

  const h2 hzero = h2{(_Float16)0.f, (_Float16)0.f};
  const h2 MXI = h2{(_Float16)-1.f, (_Float16)-1.f};
  const h2 MNI = h2{(_Float16)65504.f, (_Float16)65504.f};
  h2 psh = hzero, pqh = hzero;                                   // packed f16 stats

  const int wid  = (blockIdx.x >> 1) * 8 + wave;                 // stream id, 4096 total
  int cur        = __builtin_amdgcn_readfirstlane(waveStart[wid]);
  const int nEnd = __builtin_amdgcn_readfirstlane(waveStart[wid + 1]);

  if (cur < nEnd) {
    const int uBeg = __builtin_amdgcn_readfirstlane(offs[cur]);
    const int uEnd = __builtin_amdgcn_readfirstlane(offs[nEnd]);
    const int span = uEnd - uBeg;
    if (span > 0) {
      // stage this wave's record range to LDS (coalesced, removes records from vmcnt queue)
      for (int s = lane; s < span; s += 64) rec[wave][s] = ed[uBeg + s];

      u32 info = nodeInfo[cur];
      while ((int)(info >> 10) == uBeg) { cur++; info = nodeInfo[cur]; }
      int curEnd   = (int)(info >> 10);
      int vE       = uBeg + (int)(info & 1023u);
      u32 nextInfo = nodeInfo[cur + 1];

      h2 mx = MXI, mn = MNI;
      const int nc = span >> 2;
      u32 Z[8][4];

      auto flushNode = [&]() {
        h2 s;
        s.x = (ge0 >= 0.f) ? mx.x : mn.x;
        s.y = (ge1 >= 0.f) ? mx.y : mn.y;
        aggh[(size_t)cur * 128 + grp * 64 + lane] = h22u(s);
      };

#define ISSUEZ(ZB, CI) { \
      int _c = (CI) < nc - 1 ? (CI) : nc - 1; \
      uint4 _a = *(const uint4*)&rec[wave][_c*4]; \
      uint4 _b = *(const uint4*)&rec[wave][_c*4 + 2]; \
      Z[ZB][0] = zload(zp, _a.y >> 16); \
      Z[ZB][1] = zload(zp, _a.w >> 16); \
      Z[ZB][2] = zload(zp, _b.y >> 16); \
      Z[ZB][3] = zload(zp, _b.w >> 16); }

#define PROCSLOT(RX, RY, ZV, KOFF) { \
      h2 dxx = u2h2(((RX) & 0xffffu) | ((RX) << 16)); \
      h2 dyy = u2h2(((RX) >> 16) | ((RX) & 0xffff0000u)); \
      h2 dzz = u2h2(((RY) & 0xffffu) | ((RY) << 16)); \
      h2 y = dxx*w0 + dyy*w1 + dzz*w2 + u2h2(ZV); \
      y = __builtin_elementwise_max(y, hzero); \
      mx = __builtin_elementwise_max(mx, y); \
      mn = __builtin_elementwise_min(mn, y); \
      if (slot + (KOFF) < vE) { psh = psh + y; pqh = y*y + pqh; } }

#define PHASE(J, ZW, ZR) { \
      uint4 rA = *(const uint4*)&rec[wave][(J)*4]; \
      uint4 rB = *(const uint4*)&rec[wave][(J)*4 + 2]; \
      ISSUEZ(ZW, (J) + 5) \
      asm volatile("s_waitcnt vmcnt(20)" ::: "memory"); \
      __builtin_amdgcn_sched_barrier(0); \
      const int slot = uBeg + (J)*4; \
      if (slot == curEnd) { \
        flushNode(); \
        mx = MXI; mn = MNI; \
        cur++; \
        u32 inf = nextInfo; \
        while ((int)(inf >> 10) == curEnd) { cur++; inf = nodeInfo[cur]; } \
        vE = curEnd + (int)(inf & 1023u); \
        curEnd = (int)(inf >> 10); \
        nextInfo = nodeInfo[cur + 1]; \
      } \
      PROCSLOT(rA.x, rA.y, Z[ZR][0], 0) \
      PROCSLOT(rA.z, rA.w, Z[ZR][1], 1) \
      PROCSLOT(rB.x, rB.y, Z[ZR][2], 2) \
      PROCSLOT(rB.z, rB.w, Z[ZR][3], 3) }

      // prologue: z for chunks 0..4 (20 loads in flight, 5-phase lead)
      ISSUEZ(0, 0) ISSUEZ(1, 1) ISSUEZ(2, 2) ISSUEZ(3, 3) ISSUEZ(4, 4)

      for (int j = 0; j < nc; j += 8) {
        PHASE(j + 0, 5, 0)
        if (j + 1 < nc) PHASE(j + 1, 6, 1)
        if (j + 2 < nc) PHASE(j + 2, 7, 2)
        if (j + 3 < nc) PHASE(j + 3, 0, 3)
        if (j + 4 < nc) PHASE(j + 4, 1, 4)
        if (j + 5 < nc) PHASE(j + 5, 2, 5)
        if (j + 6 < nc) PHASE(j + 6, 3, 6)
        if (j + 7 < nc) PHASE(j + 7, 4, 7)
      }
      flushNode();
#undef ISSUEZ
#undef PROCSLOT
#undef PHASE
    }
  }

  // block-level stats reduction: block covers channels [grp*128, grp*128+128)
  float ps0 = (float)psh.x, ps1 = (float)psh.y;
  float pq0 = (float)pqh.x, pq1 = (float)pqh.y;
  red[wave][lane*2]     = ps0;
  red[wave][lane*2 + 1] = ps1;
  __syncthreads();
  if (tid < 128) {
    float s = 0.f;
    #pragma unroll
    for (int w = 0; w < 8; w++) s += red[w][tid];
    atomicAdd(&esum[grp*128 + tid], s);
  }
  __syncthreads();
  red[wave][lane*2]     = pq0;
  red[wave][lane*2 + 1] = pq1;
  __syncthreads();
  if (tid < 128) {
    float s = 0.f;
    #pragma unroll
    for (int w = 0; w < 8; w++) s += red[w][tid];
    atomicAdd(&esumsq[grp*128 + tid], s);
  }
}

// --- u GEMM (fused BN-e stats + aggnorm): A = BN(aggh) on-the-fly; y=relu(A@Wu+b) ---
__global__ __launch_bounds__(256)
void k_ugemm(const u32* __restrict__ aggh, const int* __restrict__ counts,
             const float* __restrict__ esum, const float* __restrict__ esumsq,
             const float* __restrict__ ge, const float* __restrict__ bte,
             const u16* __restrict__ WuT, const float* __restrict__ bu,
             u16* __restrict__ yu, float* __restrict__ usum, float* __restrict__ usumsq)
{
  __shared__ __align__(16) u16 As[128*32];
  __shared__ __align__(16) u16 Bs[128*32];
  __shared__ float sscale[256], sshift[256];
  const int t  = threadIdx.x;
  const int n0 = blockIdx.x * 128;
  const int mb = blockIdx.y * 128;

  {  // fused k_stats_e (redundant per block, trivial)
    float m = esum[t] / (float)M_EDGE;
    float v = esumsq[t] / (float)M_EDGE - m*m;
    v = fmaxf(v, 0.f);
    float s = ge[t] * rsqrtf(v + EPS_);
    sscale[t] = s;
    sshift[t] = bte[t] - m*s;
  }

  int r0 = mb + (t >> 2);      if (r0 >= M_NODE) r0 = 0;
  int r1 = mb + 64 + (t >> 2); if (r1 >= M_NODE) r1 = 0;
  const int ak = (((t & 3) ^ ((t >> 3) & 3)) << 3);
  const bool nz0 = counts[r0] > 0;
  const bool nz1 = counts[r1] > 0;
  const u32* ag0 = aggh + (size_t)r0 * 128 + (ak >> 1);
  const u32* ag1 = aggh + (size_t)r1 * 128 + (ak >> 1);
  const u16* bsrc0 = WuT + (size_t)(n0 + (t >> 2)) * C_ + ak;
  const u16* bsrc1 = WuT + (size_t)(n0 + 64 + (t >> 2)) * C_ + ak;

  const f32x4 zero = {0.f, 0.f, 0.f, 0.f};
  f32x4 acc[4][4];
  #pragma unroll
  for (int m = 0; m < 4; m++)
    #pragma unroll
    for (int n = 0; n < 4; n++) acc[m][n] = zero;

  const int lane = t & 63, wave = t >> 6;
  const int wr = wave >> 1, wc = wave & 1;
  const int lr = lane & 15, lch = lane >> 4;
  const int swz = (lr >> 1) & 3;

  __syncthreads();   // sscale/sshift ready

  for (int kk = 0; kk < 8; kk++) {
    const int k0 = kk * 32;
    // A staging: packed-f16 aggh -> BN affine -> bf16 tile (replaces k_aggnorm)
    uint4 a0 = *(const uint4*)(ag0 + (k0 >> 1));
    uint4 a1 = *(const uint4*)(ag1 + (k0 >> 1));
    const int base = k0 + ak;
    float4 sc0 = *(const float4*)&sscale[base];
    float4 sc1 = *(const float4*)&sscale[base + 4];
    float4 sh0 = *(const float4*)&sshift[base];
    float4 sh1 = *(const float4*)&sshift[base + 4];
    auto cvt = [&](u32 q, float s0, float b0, float s1, float b1, bool nz) -> u32 {
      float v0 = nz ? fmaf(h2f(q & 0xffffu), s0, b0) : 0.f;
      float v1 = nz ? fmaf(h2f(q >> 16),     s1, b1) : 0.f;
      return ((u32)f2bf(v0)) | (((u32)f2bf(v1)) << 16);
    };
    uint4 p0, p1;
    p0.x = cvt(a0.x, sc0.x, sh0.x, sc0.y, sh0.y, nz0);
    p0.y = cvt(a0.y, sc0.z, sh0.z, sc0.w, sh0.w, nz0);
    p0.z = cvt(a0.z, sc1.x, sh1.x, sc1.y, sh1.y, nz0);
    p0.w = cvt(a0.w, sc1.z, sh1.z, sc1.w, sh1.w, nz0);
    p1.x = cvt(a1.x, sc0.x, sh0.x, sc0.y, sh0.y, nz1);
    p1.y = cvt(a1.y, sc0.z, sh0.z, sc0.w, sh0.w, nz1);
    p1.z = cvt(a1.z, sc1.x, sh1.x, sc1.y, sh1.y, nz1);
    p1.w = cvt(a1.w, sc1.z, sh1.z, sc1.w, sh1.w, nz1);
    *(uint4*)&As[t*8]       = p0;
    *(uint4*)&As[(t+256)*8] = p1;
    async16(&Bs[t*8],        bsrc0 + k0);
    async16(&Bs[(t+256)*8],  bsrc1 + k0);
    __syncthreads();
    bf16x8 a[4], b[4];
    #pragma unroll
    for (int m = 0; m < 4; m++)
      a[m] = *(const bf16x8*)&As[(wr*64 + m*16 + lr)*32 + ((lch ^ swz) << 3)];
    #pragma unroll
    for (int n = 0; n < 4; n++)
      b[n] = *(const bf16x8*)&Bs[(wc*64 + n*16 + lr)*32 + ((lch ^ swz) << 3)];
    #pragma unroll
    for (int m = 0; m < 4; m++)
      #pragma unroll
      for (int n = 0; n < 4; n++)
        acc[m][n] = __builtin_amdgcn_mfma_f32_16x16x32_bf16(a[m], b[n], acc[m][n], 0, 0, 0);
    __syncthreads();
  }

  int gc[4]; float bias[4];
  #pragma unroll
  for (int n = 0; n < 4; n++) { int c = n0 + wc*64 + n*16 + lr; gc[n] = c; bias[n] = bu[c]; }
  float psum[4] = {0.f,0.f,0.f,0.f};
  float psq [4] = {0.f,0.f,0.f,0.f};
  #pragma unroll
  for (int m = 0; m < 4; m++) {
    #pragma unroll
    for (int j = 0; j < 4; j++) {
      int r = mb + wr*64 + m*16 + lch*4 + j;
      bool valid = r < M_NODE;
      #pragma unroll
      for (int n = 0; n < 4; n++) {
        float y = fmaxf(acc[m][n][j] + bias[n], 0.f);
        if (valid) {
          psum[n] += y;
          psq[n]  += y*y;
          yu[(size_t)r * C_ + gc[n]] = f2bf(y);
        }
      }
    }
  }
  #pragma unroll
  for (int n = 0; n < 4; n++) {
    float s1 = psum[n], s2 = psq[n];
    s1 += __shfl_xor(s1, 16, 64);  s2 += __shfl_xor(s2, 16, 64);
    s1 += __shfl_xor(s1, 32, 64);  s2 += __shfl_xor(s2, 32, 64);
    if (lch == 0) { atomicAdd(&usum[gc[n]], s1); atomicAdd(&usumsq[gc[n]], s2); }
  }
}

// -- final (fused BN-u stats): BN affine + residual (bf16 vf) + transpose to [B][C][N] --
__global__ void k_final(const u16* __restrict__ yu, const u16* __restrict__ vf,
                        const float* __restrict__ usum, const float* __restrict__ usumsq,
                        const float* __restrict__ gu, const float* __restrict__ btu,
                        float* __restrict__ out) {
  __shared__ float tile[32][33];
  __shared__ float sc[32], sh[32];
  int tx = threadIdx.x & 31, ty = threadIdx.x >> 5;
  int b = blockIdx.z, c0 = blockIdx.y * 32, n0 = blockIdx.x * 32;
  if (threadIdx.x < 32) {   // fused k_stats_u for this block's 32 channels
    int c = c0 + threadIdx.x;
    float m = usum[c] / (float)M_NODE;
    float v = usumsq[c] / (float)M_NODE - m*m;
    v = fmaxf(v, 0.f);
    float s = gu[c] * rsqrtf(v + EPS_);
    sc[threadIdx.x] = s;
    sh[threadIdx.x] = btu[c] - m*s;
  }
  __syncthreads();
  #pragma unroll
  for (int i = 0; i < 4; i++) {
    int n = n0 + ty + i*8, c = c0 + tx;
    float v = 0.f;
    if (n < N_) {
      size_t idx = ((size_t)(b*N_ + n))*C_ + c;
      v = bf2f(yu[idx]) * sc[tx] + sh[tx] + bf2f(vf[idx]);
    }
    tile[ty + i*8][tx] = v;
  }
  __syncthreads();
  int n = n0 + tx;
  if (n < N_) {
    #pragma unroll
    for (int i = 0; i < 4; i++) {
      int c = c0 + ty + i*8;
      out[((size_t)(b*C_ + c))*N_ + n] = tile[tx][ty + i*8];
    }
  }
}

extern "C" void kernel_launch(void* const* d_in, const int* in_sizes, int n_in,
                              void* d_out, int out_size, void* d_ws, size_t ws_size,
                              hipStream_t stream) {
  const float* xyz  = (const float*)d_in[0];
  const float* feat = (const float*)d_in[1];
  const int*   edges= (const int*)  d_in[2];
  const float* We   = (const float*)d_in[3];
  const float* be   = (const float*)d_in[4];
  const float* ge   = (const float*)d_in[5];
  const float* bte  = (const float*)d_in[6];
  const float* Wu   = (const float*)d_in[7];
  const float* bu   = (const float*)d_in[8];
  const float* gu   = (const float*)d_in[9];
  const float* btu  = (const float*)d_in[10];
  float* out = (float*)d_out;

  char* w = (char*)d_ws;
  size_t off = 0;
  auto carve = [&](size_t bytes) -> void* {
    void* p = w + off;
    off = (off + bytes + 511) & ~(size_t)511;
    return p;
  };
  u16*  vf       = (u16*) carve((size_t)M_NODE*C_*2);       // 10.24 MB
  u16*  WeT      = (u16*) carve((size_t)C_*C_*2);
  u16*  WuT      = (u16*) carve((size_t)C_*C_*2);
  u16*  zh       = (u16*) carve((size_t)M_NODE*C_*2);       // 10.24 MB (fp16)
  uint2* ed      = (uint2*)carve((size_t)ED_CAP*8);         // 2.9 MB
  int*  counts   = (int*) carve((size_t)M_NODE*4);
  int*  offs     = (int*) carve((size_t)(M_NODE+1)*4);
  int*  cursor   = (int*) carve((size_t)M_NODE*4);
  u32*  nodeInfo = (u32*) carve((size_t)(M_NODE+2)*4);
  int*  waveStart= (int*) carve((size_t)(NW_+1)*4);
  u32*  aggh     = (u32*) carve((size_t)M_NODE*128*4);      // 10.24 MB (packed f16)
  u16*  yu       = (u16*) carve((size_t)M_NODE*C_*2);       // 10.24 MB (bf16)
  float* stats   = (float*)carve(2048*4);
  float* esum = stats,        *esumsq = stats + 256;
  float* usum = stats + 512,  *usumsq = stats + 768;

  k_transpose_feat<<<dim3((N_+31)/32, C_/32, 3), 256, 0, stream>>>(
      feat, vf, We, Wu, WeT, WuT, counts, stats);
  k_hist<<<dim3((M_EDGE + 255)/256), 256, 0, stream>>>(edges, counts);
  k_scan<<<1, 1024, 0, stream>>>(counts, offs, cursor);
  k_scatter<<<dim3((M_EDGE + 255)/256), 256, 0, stream>>>(edges, xyz, cursor, ed);
  k_pad<<<dim3((M_NODE + 255)/256), 256, 0, stream>>>(offs, counts, ed, nodeInfo, waveStart);
  k_zgemm<<<dim3(2, (M_NODE + 127)/128), 256, 0, stream>>>(vf, WeT, be, zh);
  k_agg<<<dim3(NW_/8*2), 512, 0, stream>>>(zh, ed, offs, nodeInfo, waveStart,
                                           We, ge, aggh, esum, esumsq);
  k_ugemm<<<dim3(2, (M_NODE + 127)/128), 256, 0, stream>>>(
      aggh, counts, esum, esumsq, ge, bte, WuT, bu, yu, usum, usumsq);
  k_final<<<dim3((N_+31)/32, C_/32, B_), 256, 0, stream>>>(
      yu, vf, usum, usumsq, gu, btu, out);
}